// Round 6
// baseline (248.952 us; speedup 1.0000x reference)
//
#include <hip/hip_runtime.h>

typedef _Float16 f16;
typedef _Float16 f16x8 __attribute__((ext_vector_type(8)));
typedef float f32x4 __attribute__((ext_vector_type(4)));

// async global->LDS, 16B per lane; LDS dest = wave-uniform base + lane*16
#define GLD16(g, l) __builtin_amdgcn_global_load_lds( \
    (const __attribute__((address_space(1))) void*)(g), \
    (__attribute__((address_space(3))) void*)(l), 16, 0, 0)

// ---------------------------------------------------------------------------
// Generic f16 MFMA GEMM, BK=64: C[m][n] = sum_k A[m][k]*B[n][k] (+bias)
// A: [M][K] f16 row-major, B: [N][K] f16 row-major (B^T layout).
// MODE: 0 none, 1 bias[col], 2 bias[row], 3 split-QK (col<768 -> C else C2).
// 256 threads = 4 waves (2x2); wave tile (BM/2)x(BN/2); MFMA 16x16x32_f16,
// two k-groups per K-step. Two-barrier single-buffer K-loop (R0-proven;
// schedule variants R2/R4 and tile variants R1/R5 all neutral-or-worse).
// LDS row = 64 f16 = 128 B; XOR swizzle: slot s of row r holds global chunk
// s^(r&7) -> ds_read_b128 bank-spread. Staging: one GLD16 issue = 8 rows.
//
// R6 addition: XCD-chunked block swizzle (T1). Hardware dispatches linear
// block id round-robin across 8 XCDs with private (incoherent) L2s; panel-
// sharing neighbor blocks land on different XCDs and re-fetch from L3/HBM.
// Remap so hardware-order id `lin` computes tile (lin%8)*(nwg/8)+lin/8:
// each XCD gets a contiguous tile chunk -> shared A/B panels become L2-hits.
// Bijective because every grid here has nwg%8==0 per z-slice.
// ---------------------------------------------------------------------------
template <typename OutT, int BM, int BN, int MODE, int MINW>
__global__ __launch_bounds__(256, MINW)
void gemm_kernel(const f16* __restrict__ A, long sA,
                 const f16* __restrict__ B, long sB,
                 void* __restrict__ Cv, long sC,
                 void* __restrict__ C2v,
                 const float* __restrict__ bias,
                 const float* __restrict__ bias2,
                 int N, int K)
{
    constexpr int FM = BM / 32;
    constexpr int FN = BN / 32;
    constexpr int IA = BM / 32;
    constexpr int IB = BN / 32;

    OutT* C  = (OutT*)Cv;
    OutT* C2 = (OutT*)C2v;
    const int tid  = threadIdx.x;
    const int wave = tid >> 6;
    const int lane = tid & 63;
    const int bz   = blockIdx.z;
    A += (long)bz * sA;
    B += (long)bz * sB;
    C += (long)bz * sC;

    // XCD-chunked swizzle (T1): lin = hw dispatch order within this z-slice.
    const int gx  = gridDim.x;
    const int nwg = gx * gridDim.y;
    int lin = blockIdx.x + gx * blockIdx.y;
    lin = (lin & 7) * (nwg >> 3) + (lin >> 3);     // nwg % 8 == 0 for all uses
    const int bxi = lin % gx;
    const int byi = lin / gx;
    const long bm = (long)bxi * BM;
    const long bn = (long)byi * BN;

    __shared__ f16 sAt[BM * 64];
    __shared__ f16 sBt[BN * 64];

    const int srow = lane >> 3;
    const int gch  = ((lane & 7) ^ srow) * 8;

    const f16* gAb = A + (bm + wave * (BM / 4) + srow) * (long)K + gch;
    const f16* gBb = B + (bn + wave * (BN / 4) + srow) * (long)K + gch;

    const int wm = (wave >> 1) * (BM / 2);
    const int wn = (wave & 1) * (BN / 2);
    const int lr = lane & 15;
    const int qd = lane >> 4;
    const int swz0 = ((0 * 4 + qd) ^ (lr & 7)) * 8;
    const int swz1 = ((1 * 4 + qd) ^ (lr & 7)) * 8;

    f32x4 acc[FM][FN] = {};

    for (int k0 = 0; k0 < K; k0 += 64) {
        #pragma unroll
        for (int i = 0; i < IA; ++i)
            GLD16(gAb + k0 + (long)i * 8 * K, &sAt[(wave * (BM / 4) + i * 8) * 64]);
        #pragma unroll
        for (int i = 0; i < IB; ++i)
            GLD16(gBb + k0 + (long)i * 8 * K, &sBt[(wave * (BN / 4) + i * 8) * 64]);
        __syncthreads();

        #pragma unroll
        for (int h = 0; h < 2; ++h) {
            const int swz = h ? swz1 : swz0;
            f16x8 af[FM], bf[FN];
            #pragma unroll
            for (int t = 0; t < FM; ++t)
                af[t] = *(const f16x8*)&sAt[(wm + t * 16 + lr) * 64 + swz];
            #pragma unroll
            for (int t = 0; t < FN; ++t)
                bf[t] = *(const f16x8*)&sBt[(wn + t * 16 + lr) * 64 + swz];
            #pragma unroll
            for (int tm = 0; tm < FM; ++tm)
                #pragma unroll
                for (int tn = 0; tn < FN; ++tn)
                    acc[tm][tn] = __builtin_amdgcn_mfma_f32_16x16x32_f16(
                        af[tm], bf[tn], acc[tm][tn], 0, 0, 0);
        }
        __syncthreads();
    }

    // epilogue: C/D layout col = lane&15, row = (lane>>4)*4 + reg
    #pragma unroll
    for (int tn = 0; tn < FN; ++tn) {
        const long col = bn + wn + tn * 16 + lr;
        OutT* dst = C;
        long cc = col, stride = N;
        float bc = 0.f;
        if (MODE == 1) bc = bias[col];
        if (MODE == 3) {
            stride = 768;
            if (col >= 768) { dst = C2; cc = col - 768; bc = bias2[cc]; }
            else            { bc = bias[cc]; }
        }
        #pragma unroll
        for (int tm = 0; tm < FM; ++tm) {
            #pragma unroll
            for (int r = 0; r < 4; ++r) {
                const long row = bm + wm + tm * 16 + qd * 4 + r;
                float v = acc[tm][tn][r] + bc;
                if (MODE == 2) v += bias[row];
                dst[row * stride + cc] = (OutT)v;
            }
        }
    }
}

// ---------------------------------------------------------------------------
// In-place row softmax over f16 scores; one block per row of 2048.
// fp32 math, unscaled (faithful to reference). No inter-block reuse ->
// XCD swizzle not applicable (measured null on streaming ops).
// ---------------------------------------------------------------------------
__global__ __launch_bounds__(256)
void softmax_kernel(f16* __restrict__ S)
{
    const long row = blockIdx.x;
    f16* p = S + row * 2048;
    const int tid  = threadIdx.x;
    const int wave = tid >> 6;
    const int lane = tid & 63;

    f16x8 x = *(const f16x8*)&p[tid * 8];
    float v[8];
    float m = -1e30f;
    #pragma unroll
    for (int j = 0; j < 8; ++j) { v[j] = (float)x[j]; m = fmaxf(m, v[j]); }
    #pragma unroll
    for (int off = 32; off > 0; off >>= 1) m = fmaxf(m, __shfl_down(m, off));

    __shared__ float rm[4], rs[4];
    if (lane == 0) rm[wave] = m;
    __syncthreads();
    m = fmaxf(fmaxf(rm[0], rm[1]), fmaxf(rm[2], rm[3]));

    float s = 0.f;
    #pragma unroll
    for (int j = 0; j < 8; ++j) { v[j] = __expf(v[j] - m); s += v[j]; }
    #pragma unroll
    for (int off = 32; off > 0; off >>= 1) s += __shfl_down(s, off);
    if (lane == 0) rs[wave] = s;
    __syncthreads();
    s = rs[0] + rs[1] + rs[2] + rs[3];
    const float inv = 1.0f / s;

    f16x8 y;
    #pragma unroll
    for (int j = 0; j < 8; ++j) y[j] = (f16)(v[j] * inv);
    *(f16x8*)&p[tid * 8] = y;
}

// ---------------------------------------------------------------------------
// fused fp32 -> f16 convert: blocks [0,3072) do x (6.29M elems),
// blocks [3072, 4224) do the 4 weight matrices (589824 elems each).
// ---------------------------------------------------------------------------
__global__ __launch_bounds__(256)
void cvt_all_kernel(const float* __restrict__ x,
                    const float* __restrict__ w0, const float* __restrict__ w1,
                    const float* __restrict__ w2, const float* __restrict__ w3,
                    f16* __restrict__ x16, f16* __restrict__ w16)
{
    const float* in; f16* out; long i;
    if (blockIdx.x < 3072) {
        in = x; out = x16;
        i = ((long)blockIdx.x * 256 + threadIdx.x) * 8;
    } else {
        const int wb  = blockIdx.x - 3072;
        const int sel = wb / 288;
        in  = (sel == 0) ? w0 : (sel == 1) ? w1 : (sel == 2) ? w2 : w3;
        out = w16 + (long)sel * 589824;
        i = ((long)(wb - sel * 288) * 256 + threadIdx.x) * 8;
    }
    float4 a = *(const float4*)(in + i);
    float4 b = *(const float4*)(in + i + 4);
    f16x8 o;
    o[0] = (f16)a.x; o[1] = (f16)a.y; o[2] = (f16)a.z; o[3] = (f16)a.w;
    o[4] = (f16)b.x; o[5] = (f16)b.y; o[6] = (f16)b.z; o[7] = (f16)b.w;
    *(f16x8*)&out[i] = o;
}

// ---------------------------------------------------------------------------
// B=4, S=2048, D=H=768.  ws layout (bytes):
//   x16 @0  (12.6MB) | w16 @12582912 (4.7MB: wq,wk,wv,wo) | Q @17301504
//   K @29884416 | VT @42467328 ([4][768][2048]) | S @55050240 (33.5MB)
//   Y @88604672      total ~101 MB
// ---------------------------------------------------------------------------
extern "C" void kernel_launch(void* const* d_in, const int* in_sizes, int n_in,
                              void* d_out, int out_size, void* d_ws, size_t ws_size,
                              hipStream_t stream)
{
    const float* x  = (const float*)d_in[0];
    const float* wq = (const float*)d_in[1];
    const float* bq = (const float*)d_in[2];
    const float* wk = (const float*)d_in[3];
    const float* bk = (const float*)d_in[4];
    const float* wv = (const float*)d_in[5];
    const float* bv = (const float*)d_in[6];
    const float* wo = (const float*)d_in[7];
    const float* bo = (const float*)d_in[8];

    char* ws = (char*)d_ws;
    f16* x16 = (f16*)(ws + 0);
    f16* w16 = (f16*)(ws + 12582912);
    f16* Q   = (f16*)(ws + 17301504);
    f16* Kb  = (f16*)(ws + 29884416);
    f16* VT  = (f16*)(ws + 42467328);
    f16* S   = (f16*)(ws + 55050240);
    f16* Y   = (f16*)(ws + 88604672);

    f16* wv16 = w16 + 2 * 589824;
    f16* wo16 = w16 + 3 * 589824;

    cvt_all_kernel<<<4224, 256, 0, stream>>>(x, wq, wk, wv, wo, x16, w16);

    // All grids: nwg per z-slice % 8 == 0 (required by the T1 swizzle).
    // fused Q|K projection: B = [wq;wk], N=1536, 768 blocks = 3/CU.
    // Chunk = 96 tiles = 1.5 x-rows: weight-panel shared by 64 blocks in-XCD.
    gemm_kernel<f16, 128, 128, 3, 3><<<dim3(64, 12, 1), 256, 0, stream>>>(
        x16, 0, w16, 0, Q, 0, Kb, bq, bk, 1536, 768);
    // VT[b][h][s] (row-bias, swapped operands), 64x128, 768 blocks = 3/CU.
    gemm_kernel<f16, 64, 128, 2, 4><<<dim3(12, 16, 4), 256, 0, stream>>>(
        wv16, 0, x16, (long)2048 * 768, VT, (long)768 * 2048, nullptr,
        bv, nullptr, 2048, 768);
    // S[b] = Q[b] @ K[b]^T, 128x256, 512 blocks = 2/CU. Chunk = 16 tiles =
    // one full x-row: ONE K-panel (384 KB) + 16 Q-panels (3 MB) ~= one L2.
    gemm_kernel<f16, 128, 256, 0, 2><<<dim3(16, 8, 4), 256, 0, stream>>>(
        Q, (long)2048 * 768, Kb, (long)2048 * 768, S, (long)2048 * 2048,
        nullptr, nullptr, nullptr, 2048, 768);
    softmax_kernel<<<8192, 256, 0, stream>>>(S);
    // Y[b] = P[b] @ V[b], 128x64, 768 blocks = 3/CU, K=2048. Chunk = 24
    // tiles = 2 y-rows: S-panels now L2-served instead of L3/HBM re-fetch.
    gemm_kernel<f16, 128, 64, 0, 4><<<dim3(16, 12, 4), 256, 0, stream>>>(
        S, (long)2048 * 2048, VT, (long)768 * 2048, Y, (long)2048 * 768,
        nullptr, nullptr, nullptr, 768, 2048);
    // out = Y @ wo^T + bo (fp32 out), 128x64, 768 blocks = 3/CU.
    gemm_kernel<float, 128, 64, 1, 4><<<dim3(64, 12, 1), 256, 0, stream>>>(
        Y, 0, wo16, 0, (float*)d_out, 0, nullptr, bo, nullptr, 768, 768);
}

// Round 7
// 235.354 us; speedup vs baseline: 1.0578x; 1.0578x over previous
//
#include <hip/hip_runtime.h>

typedef _Float16 f16;
typedef _Float16 f16x8 __attribute__((ext_vector_type(8)));
typedef float f32x4 __attribute__((ext_vector_type(4)));

// async global->LDS, 16B per lane; LDS dest = wave-uniform base + lane*16
#define GLD16(g, l) __builtin_amdgcn_global_load_lds( \
    (const __attribute__((address_space(1))) void*)(g), \
    (__attribute__((address_space(3))) void*)(l), 16, 0, 0)

// ---------------------------------------------------------------------------
// Generic f16 MFMA GEMM, BK=64: C[m][n] = sum_k A[m][k]*B[n][k] (+bias)
// A: [M][K] f16 row-major, B: [N][K] f16 row-major (B^T layout).
// MODE: 0 none, 1 bias[col], 2 bias[row], 3 split-QK (col<768 -> C else C2).
// 256 threads = 4 waves (2x2); wave tile (BM/2)x(BN/2); MFMA 16x16x32_f16,
// two k-groups per K-step. Two-barrier single-buffer K-loop.
// LDS row = 64 f16 = 128 B; XOR swizzle: slot s of row r holds global chunk
// s^(r&7) -> ds_read_b128 bank-spread. Staging: one GLD16 issue = 8 rows.
//
// Session ledger (falsified levers -- do not retry):
//  R1 128x128@1.5blk/CU: -14us (occupancy loss beats LDS-ratio gain)
//  R2 coarse counted-vmcnt dbuf: neutral   R4 fine ring BK=32: -30us
//  R5 96-wide tiles @2blk/CU: -9us         R6 XCD chunk-swizzle: -19us
//    (R6 PV FETCH 65->139MB: default round-robin already L2-optimal for 2D
//     grids -- each XCD gets 2 A-panels x all B-panels ~= 4MB = one L2)
// R7 lever: waves/CU (S-GEMM was 8 waves/CU, all others 12; S = slowest
// GEMM per FLOP with lowest occupancy 18.9% -> wave-starved, not LDS-bound).
// ---------------------------------------------------------------------------
template <typename OutT, int BM, int BN, int MODE, int MINW>
__global__ __launch_bounds__(256, MINW)
void gemm_kernel(const f16* __restrict__ A, long sA,
                 const f16* __restrict__ B, long sB,
                 void* __restrict__ Cv, long sC,
                 void* __restrict__ C2v,
                 const float* __restrict__ bias,
                 const float* __restrict__ bias2,
                 int N, int K)
{
    constexpr int FM = BM / 32;
    constexpr int FN = BN / 32;
    constexpr int IA = BM / 32;
    constexpr int IB = BN / 32;

    OutT* C  = (OutT*)Cv;
    OutT* C2 = (OutT*)C2v;
    const int tid  = threadIdx.x;
    const int wave = tid >> 6;
    const int lane = tid & 63;
    const int bz   = blockIdx.z;
    A += (long)bz * sA;
    B += (long)bz * sB;
    C += (long)bz * sC;
    const long bm = (long)blockIdx.x * BM;
    const long bn = (long)blockIdx.y * BN;

    __shared__ f16 sAt[BM * 64];
    __shared__ f16 sBt[BN * 64];

    const int srow = lane >> 3;
    const int gch  = ((lane & 7) ^ srow) * 8;

    const f16* gAb = A + (bm + wave * (BM / 4) + srow) * (long)K + gch;
    const f16* gBb = B + (bn + wave * (BN / 4) + srow) * (long)K + gch;

    const int wm = (wave >> 1) * (BM / 2);
    const int wn = (wave & 1) * (BN / 2);
    const int lr = lane & 15;
    const int qd = lane >> 4;
    const int swz0 = ((0 * 4 + qd) ^ (lr & 7)) * 8;
    const int swz1 = ((1 * 4 + qd) ^ (lr & 7)) * 8;

    f32x4 acc[FM][FN] = {};

    for (int k0 = 0; k0 < K; k0 += 64) {
        #pragma unroll
        for (int i = 0; i < IA; ++i)
            GLD16(gAb + k0 + (long)i * 8 * K, &sAt[(wave * (BM / 4) + i * 8) * 64]);
        #pragma unroll
        for (int i = 0; i < IB; ++i)
            GLD16(gBb + k0 + (long)i * 8 * K, &sBt[(wave * (BN / 4) + i * 8) * 64]);
        __syncthreads();

        #pragma unroll
        for (int h = 0; h < 2; ++h) {
            const int swz = h ? swz1 : swz0;
            f16x8 af[FM], bf[FN];
            #pragma unroll
            for (int t = 0; t < FM; ++t)
                af[t] = *(const f16x8*)&sAt[(wm + t * 16 + lr) * 64 + swz];
            #pragma unroll
            for (int t = 0; t < FN; ++t)
                bf[t] = *(const f16x8*)&sBt[(wn + t * 16 + lr) * 64 + swz];
            #pragma unroll
            for (int tm = 0; tm < FM; ++tm)
                #pragma unroll
                for (int tn = 0; tn < FN; ++tn)
                    acc[tm][tn] = __builtin_amdgcn_mfma_f32_16x16x32_f16(
                        af[tm], bf[tn], acc[tm][tn], 0, 0, 0);
        }
        __syncthreads();
    }

    // epilogue: C/D layout col = lane&15, row = (lane>>4)*4 + reg
    #pragma unroll
    for (int tn = 0; tn < FN; ++tn) {
        const long col = bn + wn + tn * 16 + lr;
        OutT* dst = C;
        long cc = col, stride = N;
        float bc = 0.f;
        if (MODE == 1) bc = bias[col];
        if (MODE == 3) {
            stride = 768;
            if (col >= 768) { dst = C2; cc = col - 768; bc = bias2[cc]; }
            else            { bc = bias[cc]; }
        }
        #pragma unroll
        for (int tm = 0; tm < FM; ++tm) {
            #pragma unroll
            for (int r = 0; r < 4; ++r) {
                const long row = bm + wm + tm * 16 + qd * 4 + r;
                float v = acc[tm][tn][r] + bc;
                if (MODE == 2) v += bias[row];
                dst[row * stride + cc] = (OutT)v;
            }
        }
    }
}

// ---------------------------------------------------------------------------
// In-place row softmax over f16 scores; one block per row of 2048.
// fp32 math, unscaled (faithful to reference). HBM-bound (~11 us).
// ---------------------------------------------------------------------------
__global__ __launch_bounds__(256)
void softmax_kernel(f16* __restrict__ S)
{
    const long row = blockIdx.x;
    f16* p = S + row * 2048;
    const int tid  = threadIdx.x;
    const int wave = tid >> 6;
    const int lane = tid & 63;

    f16x8 x = *(const f16x8*)&p[tid * 8];
    float v[8];
    float m = -1e30f;
    #pragma unroll
    for (int j = 0; j < 8; ++j) { v[j] = (float)x[j]; m = fmaxf(m, v[j]); }
    #pragma unroll
    for (int off = 32; off > 0; off >>= 1) m = fmaxf(m, __shfl_down(m, off));

    __shared__ float rm[4], rs[4];
    if (lane == 0) rm[wave] = m;
    __syncthreads();
    m = fmaxf(fmaxf(rm[0], rm[1]), fmaxf(rm[2], rm[3]));

    float s = 0.f;
    #pragma unroll
    for (int j = 0; j < 8; ++j) { v[j] = __expf(v[j] - m); s += v[j]; }
    #pragma unroll
    for (int off = 32; off > 0; off >>= 1) s += __shfl_down(s, off);
    if (lane == 0) rs[wave] = s;
    __syncthreads();
    s = rs[0] + rs[1] + rs[2] + rs[3];
    const float inv = 1.0f / s;

    f16x8 y;
    #pragma unroll
    for (int j = 0; j < 8; ++j) y[j] = (f16)(v[j] * inv);
    *(f16x8*)&p[tid * 8] = y;
}

// ---------------------------------------------------------------------------
// fused fp32 -> f16 convert: blocks [0,3072) do x (6.29M elems),
// blocks [3072, 4224) do the 4 weight matrices (589824 elems each).
// ---------------------------------------------------------------------------
__global__ __launch_bounds__(256)
void cvt_all_kernel(const float* __restrict__ x,
                    const float* __restrict__ w0, const float* __restrict__ w1,
                    const float* __restrict__ w2, const float* __restrict__ w3,
                    f16* __restrict__ x16, f16* __restrict__ w16)
{
    const float* in; f16* out; long i;
    if (blockIdx.x < 3072) {
        in = x; out = x16;
        i = ((long)blockIdx.x * 256 + threadIdx.x) * 8;
    } else {
        const int wb  = blockIdx.x - 3072;
        const int sel = wb / 288;
        in  = (sel == 0) ? w0 : (sel == 1) ? w1 : (sel == 2) ? w2 : w3;
        out = w16 + (long)sel * 589824;
        i = ((long)(wb - sel * 288) * 256 + threadIdx.x) * 8;
    }
    float4 a = *(const float4*)(in + i);
    float4 b = *(const float4*)(in + i + 4);
    f16x8 o;
    o[0] = (f16)a.x; o[1] = (f16)a.y; o[2] = (f16)a.z; o[3] = (f16)a.w;
    o[4] = (f16)b.x; o[5] = (f16)b.y; o[6] = (f16)b.z; o[7] = (f16)b.w;
    *(f16x8*)&out[i] = o;
}

// ---------------------------------------------------------------------------
// B=4, S=2048, D=H=768.  ws layout (bytes):
//   x16 @0  (12.6MB) | w16 @12582912 (4.7MB: wq,wk,wv,wo) | Q @17301504
//   K @29884416 | VT @42467328 ([4][768][2048]) | S @55050240 (33.5MB)
//   Y @88604672      total ~101 MB
// ---------------------------------------------------------------------------
extern "C" void kernel_launch(void* const* d_in, const int* in_sizes, int n_in,
                              void* d_out, int out_size, void* d_ws, size_t ws_size,
                              hipStream_t stream)
{
    const float* x  = (const float*)d_in[0];
    const float* wq = (const float*)d_in[1];
    const float* bq = (const float*)d_in[2];
    const float* wk = (const float*)d_in[3];
    const float* bk = (const float*)d_in[4];
    const float* wv = (const float*)d_in[5];
    const float* bv = (const float*)d_in[6];
    const float* wo = (const float*)d_in[7];
    const float* bo = (const float*)d_in[8];

    char* ws = (char*)d_ws;
    f16* x16 = (f16*)(ws + 0);
    f16* w16 = (f16*)(ws + 12582912);
    f16* Q   = (f16*)(ws + 17301504);
    f16* Kb  = (f16*)(ws + 29884416);
    f16* VT  = (f16*)(ws + 42467328);
    f16* S   = (f16*)(ws + 55050240);
    f16* Y   = (f16*)(ws + 88604672);

    f16* wv16 = w16 + 2 * 589824;
    f16* wo16 = w16 + 3 * 589824;

    cvt_all_kernel<<<4224, 256, 0, stream>>>(x, wq, wk, wv, wo, x16, w16);

    // fused Q|K projection: B = [wq;wk], N=1536, 768 blocks = 3/CU (R0).
    gemm_kernel<f16, 128, 128, 3, 3><<<dim3(64, 12, 1), 256, 0, stream>>>(
        x16, 0, w16, 0, Q, 0, Kb, bq, bk, 1536, 768);
    // VT[b][h][s] = sum_d wv[h][d] x[b][s][d] + bv[h] (row-bias, R0 shape).
    gemm_kernel<f16, 64, 128, 2, 4><<<dim3(12, 16, 4), 256, 0, stream>>>(
        wv16, 0, x16, (long)2048 * 768, VT, (long)768 * 2048, nullptr,
        bv, nullptr, 2048, 768);
    // S[b] = Q[b] @ K[b]^T -- R7 CHANGE: 128x128 tiles, grid (16,16,4) =
    // 1024 blocks = 4/CU = 16 waves/CU (was 128x256, 2/CU, 8 waves/CU,
    // occupancy 18.9%, slowest GEMM per FLOP). LDS 32KB*4 = 128KB/CU ok;
    // acc[4][4] = 64 VGPR, MINW=4 cap 128 ok.
    gemm_kernel<f16, 128, 128, 0, 4><<<dim3(16, 16, 4), 256, 0, stream>>>(
        Q, (long)2048 * 768, Kb, (long)2048 * 768, S, (long)2048 * 2048,
        nullptr, nullptr, nullptr, 2048, 768);
    softmax_kernel<<<8192, 256, 0, stream>>>(S);
    // Y[b] = P[b] @ V[b]: 128x64, 768 blocks = 3/CU, K=2048 (R0 shape).
    gemm_kernel<f16, 128, 64, 0, 4><<<dim3(16, 12, 4), 256, 0, stream>>>(
        S, (long)2048 * 2048, VT, (long)768 * 2048, Y, (long)2048 * 768,
        nullptr, nullptr, nullptr, 768, 2048);
    // out = Y @ wo^T + bo (fp32 out), 128x64, 768 blocks = 3/CU (R0 shape).
    gemm_kernel<float, 128, 64, 1, 4><<<dim3(64, 12, 1), 256, 0, stream>>>(
        Y, 0, wo16, 0, (float*)d_out, 0, nullptr, bo, nullptr, 768, 768);
}